// Round 13
// baseline (96.508 us; speedup 1.0000x reference)
//
#include <hip/hip_runtime.h>

#define D 256
#define NB 8192
#define NKC 128            // 8-elem k-chunks per 64-o panel (K=1024 packed)
#define PANEL (NKC * 512)  // 65536 bf16 elems per panel

#define SXX_STRIDE 264     // 256 + 8 pad -> staggered banks
#define SXX_ELEMS (32 * SXX_STRIDE)   // 8448 elems = 16896 B
#define H1_STRIDE 36       // padded row stride (fp32) -> aligned float4, no conflicts
#define H1_REGION 1152     // 32 * 36 floats per 32-col panel (4608 B)

typedef __bf16 bf16;
typedef bf16 bf16x8 __attribute__((ext_vector_type(8)));
typedef bf16 bf16x4 __attribute__((ext_vector_type(4)));
typedef float f32x4 __attribute__((ext_vector_type(4)));

__device__ __forceinline__ float fast_tanh(float x) {
    float e = __expf(2.f * x);
    return 1.f - 2.f / (e + 1.f);
}

// ---------------------------------------------------------------------------
// pack: coefs[l][i][o][c] fp32 -> tiled W planes in order [1,2,3,4]
// (element (o, k'=(c-1)*256+i) at panel + (k'>>3)*512 + (o&63)*8 + (k'&7));
// blocks 128..135: beta[l][o] = sum_i coefs[l][i][o][0] (c=0 folded out).
// ---------------------------------------------------------------------------
__global__ __launch_bounds__(256) void pack_kernel(const float* __restrict__ coefs,
                                                   bf16* __restrict__ Wt,
                                                   float* __restrict__ beta) {
    __shared__ float t[64 * 65];
    __shared__ float accs[4][64];
    int b = blockIdx.x;
    if (b < 128) {
        int l = b >> 6, rem = b & 63;
        int c = (rem >> 4) + 1, tl = rem & 15;
        int plane = c - 1;
        int i0 = (tl >> 2) * 64, o0 = (tl & 3) * 64;

        for (int j = threadIdx.x; j < 4096; j += 256) {
            int i = j >> 6, o = j & 63;
            t[i * 65 + o] = coefs[(((size_t)(l * 256 + i0 + i)) * 256 + (o0 + o)) * 5 + c];
        }
        __syncthreads();
        bf16* dst = Wt + (size_t)l * (4 * PANEL)
                       + ((size_t)(tl & 3) * NKC + (plane * 256 + i0) / 8) * 512;
        for (int j = threadIdx.x; j < 4096; j += 256) {
            int il = j & 7, o = (j >> 3) & 63, ih = j >> 9;
            dst[j] = (bf16)t[(ih * 8 + il) * 65 + o];
        }
    } else {
        int lidx = b - 128;
        int l = lidx >> 2, o0 = (lidx & 3) * 64;
        int o = threadIdx.x & 63, ig = threadIdx.x >> 6;
        float sum = 0.f;
        for (int m = 0; m < 64; ++m) {
            int i = ig * 64 + m;
            sum += coefs[(((size_t)(l * 256 + i)) * 256 + (o0 + o)) * 5 + 0];
        }
        accs[ig][o] = sum;
        __syncthreads();
        if (threadIdx.x < 64)
            beta[l * 256 + o0 + threadIdx.x] = accs[0][threadIdx.x] + accs[1][threadIdx.x]
                                             + accs[2][threadIdx.x] + accs[3][threadIdx.x];
    }
}

// ---------------------------------------------------------------------------
// Fused 2-layer kernel. Block = 32-row slab x 256 cols; 8 waves = 8 col-groups
// of 32, each owning FULL K=1024 (no split-K: no dump/reduce, fewer barriers,
// and each Jacobi chain is computed once per block instead of twice).
// K-loop: it = j*4 + q (i-chunk-major). q=0: one P1..P4 chain per element ->
// emit P1 fragment, cache P2/P3/P4 fragments (24 VGPR, live 3 iters).
// q=1..3: cached fragment, zero VALU. W streamed L2 -> VGPR ring (3 slots,
// prefetch distance 2); compiler inserts precise vmcnt.
// h1 stays in LDS between layers (32x36-padded fp32 panels).
// ---------------------------------------------------------------------------
__global__ __launch_bounds__(512, 2) void fused2_kernel(
    const float* __restrict__ x, const float* __restrict__ ln_scale,
    const float* __restrict__ ln_bias, const float* __restrict__ alphas,
    const bf16* __restrict__ Wt, const float* __restrict__ beta,
    float* __restrict__ out) {
    __shared__ __align__(16) bf16 sxx[SXX_ELEMS];       // 16896 B
    __shared__ __align__(16) float stagf[8 * H1_REGION]; // 36864 B  (53.8 KB total)

    const int tid = threadIdx.x;
    const int l   = tid & 63;
    const int w   = tid >> 6;       // col-group g = w (32 cols each)
    const int slab = blockIdx.x;

#pragma unroll
    for (int L = 0; L < 2; ++L) {
        const float* scale = ln_scale + L * D;
        const float* biasp = ln_bias + L * D;
        const bf16*  Wl    = Wt + (size_t)L * 4 * PANEL;
        const float* bet   = beta + L * D;

        // lane-fixed W pointer: frag(it=(j,q), tn) = lane + (q*32+j*4)*512 + tn*128
        const bf16* lane = Wl + (size_t)(w >> 1) * PANEL + (l >> 4) * 512
                              + ((w & 1) * 32 + (l & 15)) * 8;

        // --- prologue W prefetch: iters 0 (j0,q0) and 1 (j0,q1) ---
        bf16x8 wf[3][2];
#pragma unroll
        for (int s = 0; s < 2; ++s)
#pragma unroll
            for (int tn = 0; tn < 2; ++tn)
                wf[s][tn] = *(const bf16x8*)(lane + (s * 32) * 512 + tn * 128);

        const float a  = tanhf(alphas[L]);
        const float a1 = a + 1.f;
        float rB[3], rC[3];
#pragma unroll
        for (int k = 2; k < 5; k++) {
            float tk  = 2.f * k + 2.f * a;
            float iAk = 1.f / (2.f * k * (k + 2.f * a) * (tk - 2.f));
            rB[k - 2] = (tk - 1.f) * tk * (tk - 2.f) * iAk;
            rC[k - 2] = 2.f * (k + a - 1.f) * (k + a - 1.f) * tk * iAk;
        }

        float4 sc4 = ((const float4*)scale)[l];
        float4 bi4 = ((const float4*)biasp)[l];
        float scv[4] = {sc4.x, sc4.y, sc4.z, sc4.w};
        float biv[4] = {bi4.x, bi4.y, bi4.z, bi4.w};

        // --- LN + tanh -> sxx: wave w owns rows 4w..4w+3, lane i=4l..4l+3 ---
#pragma unroll
        for (int rr = 0; rr < 4; ++rr) {
            int lr = w * 4 + rr;
            float4 v;
            if (L == 0) {
                v = ((const float4*)(x + ((size_t)slab * 32 + lr) * D))[l];
            } else {
                // h1 cols 4l..4l+3 live in panel l>>3, local col 4*(l&7)
                v = *(const float4*)(stagf + (l >> 3) * H1_REGION + lr * H1_STRIDE
                                     + 4 * (l & 7));
            }
            float s  = v.x + v.y + v.z + v.w;
            float ss = v.x * v.x + v.y * v.y + v.z * v.z + v.w * v.w;
#pragma unroll
            for (int off = 32; off > 0; off >>= 1) {
                s  += __shfl_down(s, off);
                ss += __shfl_down(ss, off);
            }
            s  = __shfl(s, 0);
            ss = __shfl(ss, 0);
            float mu   = s * (1.f / D);
            float rstd = rsqrtf(ss * (1.f / D) - mu * mu + 1e-6f);
            float hv[4] = {v.x, v.y, v.z, v.w};
            bf16x4 o;
#pragma unroll
            for (int e = 0; e < 4; ++e)
                o[e] = (bf16)fast_tanh((hv[e] - mu) * rstd * scv[e] + biv[e]);
            *(bf16x4*)(sxx + lr * SXX_STRIDE + 4 * l) = o;
        }
        __syncthreads();   // sxx ready (also: all waves past prior K-loop/h1 reads)

        // --- K-loop: 32 iters, it = j*4 + q ---
        f32x4 acc[2][2] = {};
        bf16x8 pc2[2], pc3[2], pc4[2];   // cached plane fragments
#pragma unroll
        for (int j = 0; j < 8; ++j) {
#pragma unroll
            for (int q = 0; q < 4; ++q) {
                const int it = j * 4 + q;
                // prefetch it+2 into ring slot (it+2)%3
                if (it < 30) {
                    const int itp = it + 2;
                    const int jp = itp >> 2, qp = itp & 3;
                    const int s = itp % 3;
#pragma unroll
                    for (int tn = 0; tn < 2; ++tn)
                        wf[s][tn] = *(const bf16x8*)(lane + (qp * 32 + jp * 4) * 512
                                                     + tn * 128);
                }

                bf16x8 af[2];
                if (q == 0) {
                    const int i0 = j * 32 + (l >> 4) * 8;
#pragma unroll
                    for (int tm = 0; tm < 2; ++tm) {
                        bf16x8 xv = *(const bf16x8*)(sxx + (16 * tm + (l & 15)) * SXX_STRIDE + i0);
#pragma unroll
                        for (int jj = 0; jj < 8; ++jj) {
                            float xx = (float)xv[jj];
                            float P1 = a1 * xx;
                            float P2 = rB[0] * xx * P1 - rC[0];
                            float P3 = rB[1] * xx * P2 - rC[1] * P1;
                            float P4 = rB[2] * xx * P3 - rC[2] * P2;
                            af[tm][jj]  = (bf16)P1;
                            pc2[tm][jj] = (bf16)P2;
                            pc3[tm][jj] = (bf16)P3;
                            pc4[tm][jj] = (bf16)P4;
                        }
                    }
                } else if (q == 1) { af[0] = pc2[0]; af[1] = pc2[1]; }
                else if (q == 2)   { af[0] = pc3[0]; af[1] = pc3[1]; }
                else               { af[0] = pc4[0]; af[1] = pc4[1]; }

                const int cur = it % 3;
#pragma unroll
                for (int tm = 0; tm < 2; ++tm)
#pragma unroll
                    for (int tn = 0; tn < 2; ++tn)
                        acc[tm][tn] = __builtin_amdgcn_mfma_f32_16x16x32_bf16(
                            af[tm], wf[cur][tn], acc[tm][tn], 0, 0, 0);
            }
        }

        // --- epilogue: wave owns its 32x32 block outright ---
        if (L == 0) {
            float* hp = stagf + w * H1_REGION;
#pragma unroll
            for (int tm = 0; tm < 2; ++tm)
#pragma unroll
                for (int tn = 0; tn < 2; ++tn) {
                    int lc = tn * 16 + (l & 15);
                    float bv = bet[w * 32 + lc] * (1.f / 256.f);
                    int lr0 = tm * 16 + (l >> 4) * 4;   // C/D: row=(l>>4)*4+r
#pragma unroll
                    for (int r = 0; r < 4; ++r)
                        hp[(lr0 + r) * H1_STRIDE + lc] = acc[tm][tn][r] * (1.f / 256.f) + bv;
                }
        } else {
#pragma unroll
            for (int tm = 0; tm < 2; ++tm)
#pragma unroll
                for (int tn = 0; tn < 2; ++tn) {
                    int gc = w * 32 + tn * 16 + (l & 15);
                    float bv = bet[gc] * (1.f / 256.f);
                    int gr = slab * 32 + tm * 16 + (l >> 4) * 4;
#pragma unroll
                    for (int r = 0; r < 4; ++r)
                        out[(size_t)(gr + r) * D + gc] = acc[tm][tn][r] * (1.f / 256.f) + bv;
                }
        }
        __syncthreads();   // h1 visible before next layer's LN
    }
}

// ---------------------------------------------------------------------------
extern "C" void kernel_launch(void* const* d_in, const int* in_sizes, int n_in,
                              void* d_out, int out_size, void* d_ws, size_t ws_size,
                              hipStream_t stream) {
    const float* x        = (const float*)d_in[0];
    const float* coefs    = (const float*)d_in[1];
    const float* alphas   = (const float*)d_in[2];
    const float* ln_scale = (const float*)d_in[3];
    const float* ln_bias  = (const float*)d_in[4];
    float* out = (float*)d_out;

    char* ws = (char*)d_ws;
    bf16*  Wt   = (bf16*)ws;               // 1,048,576 B
    float* beta = (float*)(ws + 1048576);  // 2,048 B

    pack_kernel<<<136, 256, 0, stream>>>(coefs, Wt, beta);
    fused2_kernel<<<256, 512, 0, stream>>>(x, ln_scale, ln_bias, alphas, Wt, beta, out);
}

// Round 14
// 94.002 us; speedup vs baseline: 1.0267x; 1.0267x over previous
//
#include <hip/hip_runtime.h>

#define D 256
#define NB 8192
#define NKC 128            // 8-elem k-chunks per 64-o panel (K=1024 packed)
#define PANEL (NKC * 512)  // 65536 bf16 elems per panel

#define SXX_STRIDE 264     // 256 + 8 pad -> staggered banks
#define SXX_ELEMS (32 * SXX_STRIDE)               // 8448 elems = 16896 B
#define WREG 4096          // dump/h1 region per wave, elems (8 KB)
#define SMEM_BYTES (SXX_ELEMS * 2 + 8 * WREG * 2) // 16896 + 65536 = 82432 B

typedef __bf16 bf16;
typedef bf16 bf16x8 __attribute__((ext_vector_type(8)));
typedef bf16 bf16x4 __attribute__((ext_vector_type(4)));
typedef float f32x4 __attribute__((ext_vector_type(4)));

__device__ __forceinline__ float fast_tanh(float x) {
    float e = __expf(2.f * x);
    return 1.f - 2.f / (e + 1.f);
}

// ---------------------------------------------------------------------------
// pack: coefs[l][i][o][c] fp32 -> tiled W planes c in order [1,4,2,3]
// (element (o, k'=plane*256+i) at panel + (k'>>3)*512 + (o&63)*8 + (k'&7));
// blocks 128..135: beta[l][o] = sum_i coefs[l][i][o][0].  [r8-verified]
// ---------------------------------------------------------------------------
__global__ __launch_bounds__(256) void pack_kernel(const float* __restrict__ coefs,
                                                   bf16* __restrict__ Wt,
                                                   float* __restrict__ beta) {
    __shared__ float t[64 * 65];
    __shared__ float accs[4][64];
    int b = blockIdx.x;
    if (b < 128) {
        int l = b >> 6, rem = b & 63;
        int c = (rem >> 4) + 1, tl = rem & 15;
        int plane = (c == 1) ? 0 : (c == 4) ? 1 : (c == 2) ? 2 : 3;
        int i0 = (tl >> 2) * 64, o0 = (tl & 3) * 64;

        for (int j = threadIdx.x; j < 4096; j += 256) {
            int i = j >> 6, o = j & 63;
            t[i * 65 + o] = coefs[(((size_t)(l * 256 + i0 + i)) * 256 + (o0 + o)) * 5 + c];
        }
        __syncthreads();
        bf16* dst = Wt + (size_t)l * (4 * PANEL)
                       + ((size_t)(tl & 3) * NKC + (plane * 256 + i0) / 8) * 512;
        for (int j = threadIdx.x; j < 4096; j += 256) {
            int il = j & 7, o = (j >> 3) & 63, ih = j >> 9;
            dst[j] = (bf16)t[(ih * 8 + il) * 65 + o];
        }
    } else {
        int lidx = b - 128;
        int l = lidx >> 2, o0 = (lidx & 3) * 64;
        int o = threadIdx.x & 63, ig = threadIdx.x >> 6;
        float sum = 0.f;
        for (int m = 0; m < 64; ++m) {
            int i = ig * 64 + m;
            sum += coefs[(((size_t)(l * 256 + i)) * 256 + (o0 + o)) * 5 + 0];
        }
        accs[ig][o] = sum;
        __syncthreads();
        if (threadIdx.x < 64)
            beta[l * 256 + o0 + threadIdx.x] = accs[0][threadIdx.x] + accs[1][threadIdx.x]
                                             + accs[2][threadIdx.x] + accs[3][threadIdx.x];
    }
}

// chunk offset (elems) of BK=32 iteration-block `it` for plane-pair half PH
#define CHOFF(PH, it) (((((PH) * 2 + ((it) & 1)) * 8) + ((it) >> 1)) * 2048)

// ---------------------------------------------------------------------------
// K-loop half: W streamed DIRECTLY L2 -> VGPR ring (no LDS for W — zero
// intra-block reuse; tiled layout makes each fragment a 64-lane x 16B
// coalesced read). 4-slot ring, prefetch distance 2, compiler-inserted vmcnt.
// A-frags: plane-pairing — even iters run one P1->P4 chain from sxx, odd
// iters reuse the cached second fragment.   [r12-verified, best measured]
// ---------------------------------------------------------------------------
template <int PH>
__device__ __forceinline__ void gemm_half(f32x4 (&acc)[2][4], bf16x8 (&wf)[4][4],
                                          const bf16* __restrict__ lane,
                                          const bf16* sxx, int l, float a1,
                                          float rB0, float rB1, float rB2,
                                          float rC0, float rC1, float rC2) {
    bf16x8 afn[2];
#pragma unroll
    for (int it = 0; it < 16; ++it) {
        if (it < 14) {
            const int s = (it + 2) & 3;
#pragma unroll
            for (int tn = 0; tn < 4; ++tn)
                wf[s][tn] = *(const bf16x8*)(lane + CHOFF(PH, it + 2) + tn * 128);
        }

        bf16x8 af[2];
        if ((it & 1) == 0) {
            const int j  = it >> 1;
            const int i0 = j * 32 + (l >> 4) * 8;
#pragma unroll
            for (int tm = 0; tm < 2; ++tm) {
                bf16x8 xv = *(const bf16x8*)(sxx + (16 * tm + (l & 15)) * SXX_STRIDE + i0);
#pragma unroll
                for (int jj = 0; jj < 8; ++jj) {
                    float x  = (float)xv[jj];
                    float P1 = a1 * x;
                    float P2 = rB0 * x * P1 - rC0;
                    float P3 = rB1 * x * P2 - rC1 * P1;
                    float PA, PB;
                    if (PH == 0) { PA = P1; PB = rB2 * x * P3 - rC2 * P2; }  // c=1,4
                    else         { PA = P2; PB = P3; }                        // c=2,3
                    af[tm][jj]  = (bf16)PA;
                    afn[tm][jj] = (bf16)PB;
                }
            }
        } else {
            af[0] = afn[0];
            af[1] = afn[1];
        }

        const int cur = it & 3;
#pragma unroll
        for (int tm = 0; tm < 2; ++tm)
#pragma unroll
            for (int tn = 0; tn < 4; ++tn)
                acc[tm][tn] = __builtin_amdgcn_mfma_f32_16x16x32_bf16(
                    af[tm], wf[cur][tn], acc[tm][tn], 0, 0, 0);
    }
}

// ---------------------------------------------------------------------------
// Fused 2-layer kernel. Block = 32-row slab x all 256 cols, 8 waves =
// 4 col-panels (g) x 2 plane-pair K-halves (p). h1 stays in LDS between
// layers. W prologue loads issued BEFORE the LN phase to hide L2 latency.
// ---------------------------------------------------------------------------
__global__ __launch_bounds__(512, 2) void fused2_kernel(
    const float* __restrict__ x, const float* __restrict__ ln_scale,
    const float* __restrict__ ln_bias, const float* __restrict__ alphas,
    const bf16* __restrict__ Wt, const float* __restrict__ beta,
    float* __restrict__ out) {
    extern __shared__ __align__(16) bf16 smem[];
    bf16* sxx  = smem;                 // 16896 B
    bf16* stag = smem + SXX_ELEMS;     // 65536 B: wave w owns [w*4096, +4096) elems

    const int tid = threadIdx.x;
    const int l   = tid & 63;
    const int w   = tid >> 6;
    const int g   = w >> 1, p = w & 1;
    const int slab = blockIdx.x;

#pragma unroll
    for (int L = 0; L < 2; ++L) {
        const float* scale = ln_scale + L * D;
        const float* biasp = ln_bias + L * D;
        const bf16*  Wl    = Wt + (size_t)L * 4 * PANEL;
        const float* bet   = beta + L * D;

        // lane-fixed W pointer: frag(tn, it) = lane + CHOFF(p, it) + tn*128
        const bf16* lane = Wl + (size_t)g * PANEL + (l >> 4) * 512 + (l & 15) * 8;

        // --- prologue W prefetch (registers; overlaps LN below) ---
        bf16x8 wf[4][4];
#pragma unroll
        for (int s = 0; s < 2; ++s)
#pragma unroll
            for (int tn = 0; tn < 4; ++tn)
                wf[s][tn] = *(const bf16x8*)(lane + (p * 16 + s * 8) * 2048 + tn * 128);

        const float a  = tanhf(alphas[L]);
        const float a1 = a + 1.f;
        float rB[3], rC[3];
#pragma unroll
        for (int k = 2; k < 5; k++) {
            float tk  = 2.f * k + 2.f * a;
            float iAk = 1.f / (2.f * k * (k + 2.f * a) * (tk - 2.f));
            rB[k - 2] = (tk - 1.f) * tk * (tk - 2.f) * iAk;
            rC[k - 2] = 2.f * (k + a - 1.f) * (k + a - 1.f) * tk * iAk;
        }

        float4 sc4 = ((const float4*)scale)[l];
        float4 bi4 = ((const float4*)biasp)[l];
        float scv[4] = {sc4.x, sc4.y, sc4.z, sc4.w};
        float biv[4] = {bi4.x, bi4.y, bi4.z, bi4.w};

        // --- LN + tanh -> sxx: wave w owns rows 4w..4w+3, lane i=4l..4l+3 ---
#pragma unroll
        for (int rr = 0; rr < 4; ++rr) {
            int lr = w * 4 + rr;
            float4 v;
            if (L == 0) {
                v = ((const float4*)(x + ((size_t)slab * 32 + lr) * D))[l];
            } else {
                // h1 panel (l>>4) lives in even-wave region 2*(l>>4)
                const float* hp = (const float*)(stag + (size_t)(l >> 4) * 2 * WREG);
                v = *(const float4*)(hp + lr * 64 + (l & 15) * 4);
            }
            float s  = v.x + v.y + v.z + v.w;
            float ss = v.x * v.x + v.y * v.y + v.z * v.z + v.w * v.w;
#pragma unroll
            for (int off = 32; off > 0; off >>= 1) {
                s  += __shfl_down(s, off);
                ss += __shfl_down(ss, off);
            }
            s  = __shfl(s, 0);
            ss = __shfl(ss, 0);
            float mu   = s * (1.f / D);
            float rstd = rsqrtf(ss * (1.f / D) - mu * mu + 1e-6f);
            float hv[4] = {v.x, v.y, v.z, v.w};
            bf16x4 o;
#pragma unroll
            for (int e = 0; e < 4; ++e)
                o[e] = (bf16)fast_tanh((hv[e] - mu) * rstd * scv[e] + biv[e]);
            *(bf16x4*)(sxx + lr * SXX_STRIDE + 4 * l) = o;
        }
        __syncthreads();   // sxx ready; h1 (L=1) fully consumed -> stag reusable

        f32x4 acc[2][4] = {};
        if (p == 0) gemm_half<0>(acc, wf, lane, sxx, l, a1, rB[0], rB[1], rB[2], rC[0], rC[1], rC[2]);
        else        gemm_half<1>(acc, wf, lane, sxx, l, a1, rB[0], rB[1], rB[2], rC[0], rC[1], rC[2]);

        // --- split-K reduce: p=1 dumps into OWN stag region ---
        if (p == 1) {
            f32x4* dumpr = (f32x4*)(stag + (size_t)w * WREG);
#pragma unroll
            for (int tm = 0; tm < 2; ++tm)
#pragma unroll
                for (int tn = 0; tn < 4; ++tn)
                    dumpr[(tm * 4 + tn) * 64 + l] = acc[tm][tn];
        }
        __syncthreads();

        if (p == 0) {
            f32x4* part = (f32x4*)(stag + (size_t)(w + 1) * WREG);
            if (L == 0) {
                float* hp = (float*)(stag + (size_t)w * WREG);   // h1 panel g, 32x64 fp32
#pragma unroll
                for (int tm = 0; tm < 2; ++tm)
#pragma unroll
                    for (int tn = 0; tn < 4; ++tn) {
                        int lc = 16 * tn + (l & 15);
                        float bv = bet[g * 64 + lc] * (1.f / 256.f);
                        f32x4 v = acc[tm][tn] + part[(tm * 4 + tn) * 64 + l];
                        int lr0 = 16 * tm + (l >> 4) * 4;        // C/D: row=(l>>4)*4+r
#pragma unroll
                        for (int r = 0; r < 4; ++r)
                            hp[(lr0 + r) * 64 + lc] = v[r] * (1.f / 256.f) + bv;
                    }
            } else {
#pragma unroll
                for (int tm = 0; tm < 2; ++tm)
#pragma unroll
                    for (int tn = 0; tn < 4; ++tn) {
                        int gc = g * 64 + 16 * tn + (l & 15);
                        float bv = bet[gc] * (1.f / 256.f);
                        f32x4 v = acc[tm][tn] + part[(tm * 4 + tn) * 64 + l];
                        int gr = slab * 32 + 16 * tm + (l >> 4) * 4;
#pragma unroll
                        for (int r = 0; r < 4; ++r)
                            out[(size_t)(gr + r) * D + gc] = v[r] * (1.f / 256.f) + bv;
                    }
            }
        }
        __syncthreads();   // h1 visible before next layer's LN
    }
}

// ---------------------------------------------------------------------------
extern "C" void kernel_launch(void* const* d_in, const int* in_sizes, int n_in,
                              void* d_out, int out_size, void* d_ws, size_t ws_size,
                              hipStream_t stream) {
    const float* x        = (const float*)d_in[0];
    const float* coefs    = (const float*)d_in[1];
    const float* alphas   = (const float*)d_in[2];
    const float* ln_scale = (const float*)d_in[3];
    const float* ln_bias  = (const float*)d_in[4];
    float* out = (float*)d_out;

    char* ws = (char*)d_ws;
    bf16*  Wt   = (bf16*)ws;               // 1,048,576 B
    float* beta = (float*)(ws + 1048576);  // 2,048 B

    hipFuncSetAttribute((const void*)fused2_kernel,
                        hipFuncAttributeMaxDynamicSharedMemorySize, SMEM_BYTES);

    pack_kernel<<<136, 256, 0, stream>>>(coefs, Wt, beta);
    fused2_kernel<<<256, 512, SMEM_BYTES, stream>>>(x, ln_scale, ln_bias, alphas,
                                                    Wt, beta, out);
}